// Round 2
// baseline (25.423 us; speedup 1.0000x reference)
//
#include <hip/hip_runtime.h>

typedef int int4v __attribute__((ext_vector_type(4)));

// Exact-grid, one int4 per thread.
//  blocks [0, tok_blocks)              : tokens -> pad-replace -> count-mask -> out
//  blocks [tok_blocks, tok_blocks+cb)  : counts passthrough copy
__global__ __launch_bounds__(256) void FusedSpeculativeBase_kernel(
    const int* __restrict__ tokens,   // [B*K] int32
    const int* __restrict__ counts,   // [B]   int32
    const int* __restrict__ pad_ptr,  // [1]   int32
    int* __restrict__ out,            // [B*K + B] int32
    int n_tok_vec,                    // B*K/4
    int n_cnt_vec,                    // B/4
    int tok_blocks,                   // ceil(n_tok_vec/256)
    int row_shift)                    // log2(K/4)
{
    if (blockIdx.x < (unsigned)tok_blocks) {
        const int idx = blockIdx.x * 256 + threadIdx.x;
        if (idx >= n_tok_vec) return;
        const int pad = pad_ptr[0];
        const int npv = tokens[0];                        // value at [0,0], pre-replacement
        const int4v v = __builtin_nontemporal_load((const int4v*)tokens + idx);
        const int row = idx >> row_shift;
        const int p0  = (idx & ((1 << row_shift) - 1)) << 2;
        const int cnt = counts[row];
        int4v r;
#pragma unroll
        for (int j = 0; j < 4; ++j) {
            int t = v[j];
            t = (t == pad) ? npv : t;                     // pad replacement
            r[j] = ((p0 + j) < cnt) ? t : pad;            // keep first cnt tokens
        }
        __builtin_nontemporal_store(r, (int4v*)out + idx);
    } else {
        const int c = (blockIdx.x - tok_blocks) * 256 + threadIdx.x;
        if (c >= n_cnt_vec) return;
        const int4v cv = __builtin_nontemporal_load((const int4v*)counts + c);
        int4v* out_cnt = (int4v*)(out + ((size_t)n_tok_vec << 2));
        __builtin_nontemporal_store(cv, out_cnt + c);
    }
}

extern "C" void kernel_launch(void* const* d_in, const int* in_sizes, int n_in,
                              void* d_out, int out_size, void* d_ws, size_t ws_size,
                              hipStream_t stream) {
    const int* tokens  = (const int*)d_in[0];
    const int* counts  = (const int*)d_in[1];
    const int* pad_ptr = (const int*)d_in[2];
    int* out = (int*)d_out;

    const int n_tok = in_sizes[0];      // B*K
    const int n_b   = in_sizes[1];      // B
    const int K     = n_tok / n_b;      // 64
    const int vecs_per_row = K / 4;     // 16 (power of two)
    int row_shift = 0;
    while ((1 << row_shift) < vecs_per_row) ++row_shift;

    const int n_tok_vec = n_tok / 4;
    const int n_cnt_vec = n_b / 4;
    const int tok_blocks = (n_tok_vec + 255) / 256;
    const int cnt_blocks = (n_cnt_vec + 255) / 256;

    FusedSpeculativeBase_kernel<<<tok_blocks + cnt_blocks, 256, 0, stream>>>(
        tokens, counts, pad_ptr, out, n_tok_vec, n_cnt_vec, tok_blocks, row_shift);
}